// Round 7
// baseline (42.795 us; speedup 1.0000x reference)
//
#include <hip/hip_runtime.h>

typedef float f32x16 __attribute__((ext_vector_type(16)));
typedef short bf16x8 __attribute__((ext_vector_type(8)));

#define BLOCK 128
#define NPTS 4096
#define SEGS 64                      // 64 rows per block (2 waves x 32)
#define CHUNK 256                    // scanned points per LDS chunk
#define NCHUNK (NPTS / CHUNK)        // 16
#define SUBS (CHUNK / 32)            // 8 col-subtiles per chunk

// ---------- bf16 helpers ----------
__device__ inline unsigned int f2bf(float x) {   // RNE float->bf16 bits
    unsigned int u = __float_as_uint(x);
    return (u + 0x7FFFu + ((u >> 16) & 1)) >> 16;
}
__device__ inline float bf2f(unsigned int b) { return __uint_as_float(b << 16); }
__device__ inline unsigned int pk2(unsigned int lo, unsigned int hi) {
    return (hi << 16) | (lo & 0xFFFFu);
}

// Precompute packed MFMA operand planes (verified slot layout, absmax 0.0):
//   k0..2: -2h * h' ; k3..5: -2l * h' ; k6..8: -2h * l' ; k9: 1*hw' ; k10: 1*lw'
// Plane-separated (pA0 = k0..7, pA1 = k8..15; same for B) so both the A-frag
// load and the B staging loads are fully coalesced. Also zeroes out[0].
__global__ __launch_bounds__(256) void pack_pts(
    const float* __restrict__ x1, const float* __restrict__ x2,
    uint4* __restrict__ pA0, uint4* __restrict__ pA1,
    uint4* __restrict__ pB0, uint4* __restrict__ pB1,
    float* __restrict__ wn, int n1, int ntot, float* __restrict__ out) {
    int i = blockIdx.x * 256 + threadIdx.x;
    if (i == 0) out[0] = 0.0f;
    if (i >= ntot) return;
    const float* s = (i < n1) ? x1 + 3 * (size_t)i : x2 + 3 * (size_t)(i - n1);
    float x = s[0], y = s[1], z = s[2];
    float w = fmaf(z, z, fmaf(y, y, x * x));
    wn[i] = w;
    unsigned int hx = f2bf(x), hy = f2bf(y), hz = f2bf(z);
    unsigned int lx = f2bf(x - bf2f(hx)), ly = f2bf(y - bf2f(hy)), lz = f2bf(z - bf2f(hz));
    unsigned int hw = f2bf(w), lw = f2bf(w - bf2f(hw));
    unsigned int ax = f2bf(-2.f * bf2f(hx)), ay = f2bf(-2.f * bf2f(hy)), az = f2bf(-2.f * bf2f(hz));
    unsigned int bx = f2bf(-2.f * bf2f(lx)), by = f2bf(-2.f * bf2f(ly)), bz = f2bf(-2.f * bf2f(lz));
    const unsigned int one = 0x3F80u;
    pA0[i] = make_uint4(pk2(ax, ay), pk2(az, bx), pk2(by, bz), pk2(ax, ay));
    pA1[i] = make_uint4(pk2(az, one), pk2(one, 0u), 0u, 0u);
    pB0[i] = make_uint4(pk2(hx, hy), pk2(hz, hx), pk2(hy, hz), pk2(lx, ly));
    pB1[i] = make_uint4(pk2(lz, hw), pk2(lw, 0u), 0u, 0u);
}

// MFMA min pass. grid = Bc*2*SEGS blocks of 128 threads (2 waves).
// Each wave owns one 32-row tile (A-frag in regs); the block streams all NPTS
// scanned points through double-buffered LDS chunks (pure uint4 copies, no
// repack). Fold: run[r] = min3(run, acc0, acc1) elementwise — col-partial
// mins; butterfly over 32 cols at the end; + ||p||^2; one atomicAdd/block.
__global__ __launch_bounds__(BLOCK) void chamfer_mfma(
    const uint4* __restrict__ pA0, const uint4* __restrict__ pA1,
    const uint4* __restrict__ pB0, const uint4* __restrict__ pB1,
    const float* __restrict__ wn, int n1, int Bc,
    float inv1, float inv2, float* __restrict__ out) {
    __shared__ uint4 lds[2][2][CHUNK];   // [buf][khalf][pt] : 16KB
    __shared__ float wslot[SEGS];
    __shared__ float red[2];

    int tid = threadIdx.x;
    int lane = tid & 63, widx = tid >> 6;
    int l31 = lane & 31, blk = lane >> 5;

    int bid = blockIdx.x;
    int seg = bid % SEGS;
    int bd = bid / SEGS;
    int dir = (bd >= Bc) ? 1 : 0;
    int b = dir ? bd - Bc : bd;
    int ownOff = dir ? n1 : 0;
    int othOff = dir ? 0 : n1;
    float inv = dir ? inv2 : inv1;

    int rowBase = seg * 64;              // block's first row (within batch)
    int row0 = rowBase + widx * 32;      // wave's first row

    size_t ownIdx = (size_t)(ownOff + b * NPTS + row0 + l31);
    uint4 af4 = blk ? pA1[ownIdx] : pA0[ownIdx];
    bf16x8 afA = *(const bf16x8*)&af4;

    if (tid < SEGS) wslot[tid] = wn[ownOff + b * NPTS + rowBase + tid];

    const uint4* gB0 = pB0 + (size_t)(othOff + b * NPTS);
    const uint4* gB1 = pB1 + (size_t)(othOff + b * NPTS);

    // stage chunk 0
    lds[0][0][tid]         = gB0[tid];
    lds[0][0][tid + BLOCK] = gB0[tid + BLOCK];
    lds[0][1][tid]         = gB1[tid];
    lds[0][1][tid + BLOCK] = gB1[tid + BLOCK];
    __syncthreads();

    f32x16 run;
#pragma unroll
    for (int r = 0; r < 16; ++r) run[r] = 3.0e38f;

    f32x16 zero = {};
    for (int c = 0; c < NCHUNK; ++c) {
        int cur = c & 1;
        uint4 u00, u01, u10, u11;
        if (c + 1 < NCHUNK) {   // prefetch next chunk (in flight across MFMAs)
            int off = (c + 1) * CHUNK;
            u00 = gB0[off + tid]; u01 = gB0[off + tid + BLOCK];
            u10 = gB1[off + tid]; u11 = gB1[off + tid + BLOCK];
        }
        const uint4* lp = lds[cur][blk];
#pragma unroll
        for (int s = 0; s < SUBS; s += 2) {
            bf16x8 bf0 = *(const bf16x8*)(lp + s * 32 + l31);
            bf16x8 bf1 = *(const bf16x8*)(lp + (s + 1) * 32 + l31);
            f32x16 acc0 = __builtin_amdgcn_mfma_f32_32x32x16_bf16(afA, bf0, zero, 0, 0, 0);
            f32x16 acc1 = __builtin_amdgcn_mfma_f32_32x32x16_bf16(afA, bf1, zero, 0, 0, 0);
#pragma unroll
            for (int r = 0; r < 16; ++r)
                run[r] = fminf(run[r], fminf(acc0[r], acc1[r]));  // v_min3_f32
        }
        if (c + 1 < NCHUNK) {
            lds[cur ^ 1][0][tid]         = u00;
            lds[cur ^ 1][0][tid + BLOCK] = u01;
            lds[cur ^ 1][1][tid]         = u10;
            lds[cur ^ 1][1][tid + BLOCK] = u11;
        }
        __syncthreads();
    }

    // butterfly min over the 32 columns (within each half-wave)
#pragma unroll
    for (int m = 1; m <= 16; m <<= 1)
#pragma unroll
        for (int r = 0; r < 16; ++r)
            run[r] = fminf(run[r], __shfl_xor(run[r], m, 64));

    // C/D layout: col=lane&31, local row=(r&3)+8*(r>>2)+4*(lane>>5)
    float contrib = 0.0f;
    if (l31 == 0) {
#pragma unroll
        for (int r = 0; r < 16; ++r) {
            int lrow = (r & 3) + 8 * (r >> 2) + 4 * blk;
            contrib += run[r] + wslot[widx * 32 + lrow];
        }
    }
    contrib += __shfl_xor(contrib, 32, 64);
    if (lane == 0) red[widx] = contrib * inv;
    __syncthreads();
    if (tid == 0) atomicAdd(out, red[0] + red[1]);
}

// Fallback (no scratch / unexpected shape): direct-diff scalar path.
__global__ __launch_bounds__(256) void chamfer_direct(
    const float* __restrict__ x1, const float* __restrict__ x2,
    int Npts, int Mpts, float inv1, float inv2, float* __restrict__ out) {
    int dir = blockIdx.z;
    const float* own = dir ? x2 : x1;
    const float* oth = dir ? x1 : x2;
    int np = dir ? Mpts : Npts;
    int mp = dir ? Npts : Mpts;
    float scale = dir ? inv2 : inv1;

    int bpb = np / 256;
    int b = blockIdx.x / bpb;
    int i = (blockIdx.x % bpb) * 256 + threadIdx.x;

    const float* pp = own + ((size_t)b * np + i) * 3;
    float px = pp[0], py = pp[1], pz = pp[2];
    const float* o = oth + (size_t)b * mp * 3;

    float best = 3.0e38f;
#pragma unroll 4
    for (int j = 0; j < mp; ++j) {
        float dx = px - o[3 * j + 0];
        float dy = py - o[3 * j + 1];
        float dz = pz - o[3 * j + 2];
        float d2 = fmaf(dz, dz, fmaf(dy, dy, dx * dx));
        best = fminf(best, d2);
    }
    float s = best * scale;
    for (int off = 32; off; off >>= 1) s += __shfl_down(s, off, 64);
    __shared__ float red[4];
    int lane = threadIdx.x & 63, wid = threadIdx.x >> 6;
    if (!lane) red[wid] = s;
    __syncthreads();
    if (!threadIdx.x) atomicAdd(out, red[0] + red[1] + red[2] + red[3]);
}

extern "C" void kernel_launch(void* const* d_in, const int* in_sizes, int n_in,
                              void* d_out, int out_size, void* d_ws, size_t ws_size,
                              hipStream_t stream) {
    const float* xyz1 = (const float*)d_in[0];
    const float* xyz2 = (const float*)d_in[1];
    float* out = (float*)d_out;

    const int Bc = in_sizes[0] / (3 * NPTS);
    const int n1 = Bc * NPTS;
    const int n2 = Bc * NPTS;
    const int ntot = n1 + n2;

    size_t need = (size_t)ntot * (16 * 4 + 4);  // 4 uint4 planes + wn
    bool okShape = Bc >= 1 && in_sizes[0] == Bc * 3 * NPTS && in_sizes[1] == in_sizes[0];

    if (okShape && ws_size >= need) {
        uint4* pA0 = (uint4*)d_ws;
        uint4* pA1 = pA0 + ntot;
        uint4* pB0 = pA1 + ntot;
        uint4* pB1 = pB0 + ntot;
        float* wn = (float*)(pB1 + ntot);

        pack_pts<<<(ntot + 255) / 256, 256, 0, stream>>>(
            xyz1, xyz2, pA0, pA1, pB0, pB1, wn, n1, ntot, out);

        chamfer_mfma<<<Bc * 2 * SEGS, BLOCK, 0, stream>>>(
            pA0, pA1, pB0, pB1, wn, n1, Bc,
            1.0f / (float)n1, 1.0f / (float)n2, out);
    } else {
        hipMemsetAsync(d_out, 0, sizeof(float), stream);
        dim3 grid((in_sizes[0] / 3 / NPTS) * (NPTS / 256), 1, 2);
        chamfer_direct<<<grid, 256, 0, stream>>>(xyz1, xyz2, NPTS, NPTS,
                                                 1.0f / (float)n1, 1.0f / (float)n2, out);
    }
}

// Round 8
// 38.390 us; speedup vs baseline: 1.1147x; 1.1147x over previous
//
#include <hip/hip_runtime.h>

typedef float f32x16 __attribute__((ext_vector_type(16)));
typedef short bf16x8 __attribute__((ext_vector_type(8)));

#define BLOCK 256
#define NPTS 4096
#define SEGS 32                      // 128 rows per block
#define CHUNK 256                    // scanned points per LDS chunk
#define NCHUNK (NPTS / CHUNK)        // 16
#define SUBS (CHUNK / 32)            // 8 col-subtiles per chunk

// ---------- bf16 helpers ----------
__device__ inline unsigned int f2bf(float x) {   // RNE float->bf16 bits
    unsigned int u = __float_as_uint(x);
    return (u + 0x7FFFu + ((u >> 16) & 1)) >> 16;
}
__device__ inline float bf2f(unsigned int b) { return __uint_as_float(b << 16); }
__device__ inline unsigned int pk2(unsigned int lo, unsigned int hi) {
    return (hi << 16) | (lo & 0xFFFFu);
}

// Single fused kernel: packs A-fragments and B-records in-kernel from raw xyz
// (inputs are L2-resident; pack cost amortized), computes q.w - 2*dot via
// verified 32x32x16 bf16 MFMA slot layout:
//   k0..2: -2h * h' ; k3..5: -2l * h' ; k6..8: -2h * l' ; k9: 1*hw' ; k10: 1*lw'
// Each block: 128 rows (4 waves x 32), scans all NPTS points of the other
// cloud via double-buffered conflict-free LDS chunks; completes per-row min
// in-block; adds ||p||^2; one atomicAdd per block. No workspace.
__global__ __launch_bounds__(BLOCK) void chamfer_fused(
    const float* __restrict__ x1, const float* __restrict__ x2,
    int Bc, float inv1, float inv2, float* __restrict__ out) {
    __shared__ uint4 lds[2][2][CHUNK];   // [buf][khalf][pt] : 16KB
    __shared__ float wslot[128];         // ||p||^2 of the block's own rows
    __shared__ float red[4];

    int tid = threadIdx.x;
    int lane = tid & 63, widx = tid >> 6;
    int l31 = lane & 31, blk = lane >> 5;

    int bid = blockIdx.x;
    int seg = bid % SEGS;
    int bd = bid / SEGS;
    int dir = (bd >= Bc) ? 1 : 0;
    int b = dir ? bd - Bc : bd;
    const float* own = dir ? x2 : x1;
    const float* oth = dir ? x1 : x2;
    float inv = dir ? inv2 : inv1;

    int row0 = seg * 128 + widx * 32;    // first row of this wave (within batch)

    // ---- pack own point -> A-fragment (this lane's khalf) ----
    bf16x8 afA;
    {
        const float* p = own + ((size_t)b * NPTS + row0 + l31) * 3;
        float x = p[0], y = p[1], z = p[2];
        float w = fmaf(z, z, fmaf(y, y, x * x));
        unsigned int hx = f2bf(x), hy = f2bf(y), hz = f2bf(z);
        unsigned int lx = f2bf(x - bf2f(hx)), ly = f2bf(y - bf2f(hy)), lz = f2bf(z - bf2f(hz));
        unsigned int ax = f2bf(-2.f * bf2f(hx)), ay = f2bf(-2.f * bf2f(hy)), az = f2bf(-2.f * bf2f(hz));
        unsigned int bx = f2bf(-2.f * bf2f(lx)), by = f2bf(-2.f * bf2f(ly)), bz = f2bf(-2.f * bf2f(lz));
        const unsigned int one = 0x3F80u;
        uint4 A0 = make_uint4(pk2(ax, ay), pk2(az, bx), pk2(by, bz), pk2(ax, ay));
        uint4 A1 = make_uint4(pk2(az, one), pk2(one, 0u), 0u, 0u);
        uint4 af4 = blk ? A1 : A0;
        afA = *(const bf16x8*)&af4;
        if (!blk) wslot[widx * 32 + l31] = w;
    }

    // ---- stage chunk 0 (pack B-record in-kernel) ----
    const float* os = oth + (size_t)b * NPTS * 3;
    {
        const float* q = os + (size_t)tid * 3;
        float x = q[0], y = q[1], z = q[2];
        float w = fmaf(z, z, fmaf(y, y, x * x));
        unsigned int hx = f2bf(x), hy = f2bf(y), hz = f2bf(z);
        unsigned int lx = f2bf(x - bf2f(hx)), ly = f2bf(y - bf2f(hy)), lz = f2bf(z - bf2f(hz));
        unsigned int hw = f2bf(w), lw = f2bf(w - bf2f(hw));
        lds[0][0][tid] = make_uint4(pk2(hx, hy), pk2(hz, hx), pk2(hy, hz), pk2(lx, ly));
        lds[0][1][tid] = make_uint4(pk2(lz, hw), pk2(lw, 0u), 0u, 0u);
    }
    __syncthreads();

    f32x16 run;
#pragma unroll
    for (int r = 0; r < 16; ++r) run[r] = 3.0e38f;

    f32x16 zero = {};
    for (int c = 0; c < NCHUNK; ++c) {
        int cur = c & 1;
        float nx, ny, nz;
        if (c + 1 < NCHUNK) {   // prefetch next chunk's raw xyz
            const float* q = os + (size_t)((c + 1) * CHUNK + tid) * 3;
            nx = q[0]; ny = q[1]; nz = q[2];
        }
        const uint4* lp = lds[cur][blk];
#pragma unroll
        for (int s = 0; s < SUBS; s += 2) {
            bf16x8 bf0 = *(const bf16x8*)(lp + s * 32 + l31);
            bf16x8 bf1 = *(const bf16x8*)(lp + (s + 1) * 32 + l31);
            f32x16 acc0 = __builtin_amdgcn_mfma_f32_32x32x16_bf16(afA, bf0, zero, 0, 0, 0);
            f32x16 acc1 = __builtin_amdgcn_mfma_f32_32x32x16_bf16(afA, bf1, zero, 0, 0, 0);
#pragma unroll
            for (int r = 0; r < 16; ++r)
                run[r] = fminf(run[r], fminf(acc0[r], acc1[r]));  // v_min3_f32
        }
        if (c + 1 < NCHUNK) {
            float w = fmaf(nz, nz, fmaf(ny, ny, nx * nx));
            unsigned int hx = f2bf(nx), hy = f2bf(ny), hz = f2bf(nz);
            unsigned int lx = f2bf(nx - bf2f(hx)), ly = f2bf(ny - bf2f(hy)), lz = f2bf(nz - bf2f(hz));
            unsigned int hw = f2bf(w), lw = f2bf(w - bf2f(hw));
            lds[cur ^ 1][0][tid] = make_uint4(pk2(hx, hy), pk2(hz, hx), pk2(hy, hz), pk2(lx, ly));
            lds[cur ^ 1][1][tid] = make_uint4(pk2(lz, hw), pk2(lw, 0u), 0u, 0u);
        }
        __syncthreads();
    }

    // butterfly min over the 32 columns (within each half-wave)
#pragma unroll
    for (int m = 1; m <= 16; m <<= 1)
#pragma unroll
        for (int r = 0; r < 16; ++r)
            run[r] = fminf(run[r], __shfl_xor(run[r], m, 64));

    // C/D layout: col=lane&31, local row=(r&3)+8*(r>>2)+4*(lane>>5)
    float contrib = 0.0f;
    if (l31 == 0) {
#pragma unroll
        for (int r = 0; r < 16; ++r) {
            int lrow = (r & 3) + 8 * (r >> 2) + 4 * blk;
            contrib += run[r] + wslot[widx * 32 + lrow];
        }
    }
    contrib += __shfl_xor(contrib, 32, 64);
    if (lane == 0) red[widx] = contrib * inv;
    __syncthreads();
    if (tid == 0) atomicAdd(out, red[0] + red[1] + red[2] + red[3]);
}

// Fallback (unexpected shape): direct-diff scalar path, no scratch.
__global__ __launch_bounds__(BLOCK) void chamfer_direct(
    const float* __restrict__ x1, const float* __restrict__ x2,
    int Npts, int Mpts, float inv1, float inv2, float* __restrict__ out) {
    int dir = blockIdx.z;
    const float* own = dir ? x2 : x1;
    const float* oth = dir ? x1 : x2;
    int np = dir ? Mpts : Npts;
    int mp = dir ? Npts : Mpts;
    float scale = dir ? inv2 : inv1;

    int bpb = np / BLOCK;
    int b = blockIdx.x / bpb;
    int i = (blockIdx.x % bpb) * BLOCK + threadIdx.x;

    const float* pp = own + ((size_t)b * np + i) * 3;
    float px = pp[0], py = pp[1], pz = pp[2];
    const float* o = oth + (size_t)b * mp * 3;

    float best = 3.0e38f;
#pragma unroll 4
    for (int j = 0; j < mp; ++j) {
        float dx = px - o[3 * j + 0];
        float dy = py - o[3 * j + 1];
        float dz = pz - o[3 * j + 2];
        float d2 = fmaf(dz, dz, fmaf(dy, dy, dx * dx));
        best = fminf(best, d2);
    }
    float s = best * scale;
    for (int off = 32; off; off >>= 1) s += __shfl_down(s, off, 64);
    __shared__ float red[BLOCK / 64];
    int lane = threadIdx.x & 63, wid = threadIdx.x >> 6;
    if (!lane) red[wid] = s;
    __syncthreads();
    if (!threadIdx.x) atomicAdd(out, red[0] + red[1] + red[2] + red[3]);
}

extern "C" void kernel_launch(void* const* d_in, const int* in_sizes, int n_in,
                              void* d_out, int out_size, void* d_ws, size_t ws_size,
                              hipStream_t stream) {
    const float* xyz1 = (const float*)d_in[0];
    const float* xyz2 = (const float*)d_in[1];
    float* out = (float*)d_out;

    const int Bc = in_sizes[0] / (3 * NPTS);
    const int n1 = Bc * NPTS;
    const int n2 = Bc * NPTS;
    bool okShape = Bc >= 1 && in_sizes[0] == Bc * 3 * NPTS && in_sizes[1] == in_sizes[0];

    hipMemsetAsync(d_out, 0, sizeof(float), stream);

    if (okShape) {
        chamfer_fused<<<Bc * 2 * SEGS, BLOCK, 0, stream>>>(
            xyz1, xyz2, Bc, 1.0f / (float)n1, 1.0f / (float)n2, out);
    } else {
        dim3 grid((in_sizes[0] / 3 / NPTS) * (NPTS / BLOCK), 1, 2);
        chamfer_direct<<<grid, BLOCK, 0, stream>>>(xyz1, xyz2, NPTS, NPTS,
                                                   1.0f / (float)n1, 1.0f / (float)n2, out);
    }
}